// Round 1
// baseline (9585.955 us; speedup 1.0000x reference)
//
#include <hip/hip_runtime.h>
#include <cstdint>
#include <cstddef>

// ============================================================================
// Actor rollout: T=64 sequential steps of
//   h = GRU(x, h); dist = log_softmax(h @ w_out^T + b_out);
//   sample via eps-greedy + Gumbel (JAX threefry, bit-exact); x = emb[sample]
// Round 0: correctness-first. f32 vector-ALU GEMMs (no f32 MFMA on CDNA4).
// PRNG: JAX threefry2x32, partitionable variant (JAX >= 0.4.30 default).
// Fallback to original variant: set JAX_PARTITIONABLE 0.
// ============================================================================

#define JAX_PARTITIONABLE 1

#define Bn 64
#define Tn 64
#define Vn 32000
#define Hn 512
#define En 256

// ---------------- output layout (floats) ----------------
#define OUT_SAMP 0                      // (B,T)
#define OUT_CORR (Bn * Tn)              // (B,T)
#define OUT_LOGP (2 * Bn * Tn)          // (B,T)
#define OUT_DIST (3 * Bn * Tn)          // (B,T,V) at [((b*T)+t)*V + v]
#define OUT_PROB (3 * Bn * Tn + (size_t)Bn * Tn * Vn)  // (T,V)

// ---------------- ws layout (floats/ints) ----------------
#define WS_H0     0            // B*H
#define WS_H1     (Bn * Hn)    // B*H
#define WS_G      (2 * Bn * Hn)            // B*1536
#define WS_GHN    (WS_G + Bn * 3 * Hn)     // B*512
#define WS_RMAX   (WS_GHN + Bn * Hn)       // 64
#define WS_RLSE   (WS_RMAX + Bn)           // 64
#define WS_BSC    (WS_RLSE + Bn)           // 64*8
#define WS_BDI    (WS_BSC + Bn * 8)        // 64*8
#define WS_BIX    (WS_BDI + Bn * 8)        // 64*8 (int)
#define WS_SMP    (WS_BIX + Bn * 8)        // 64 (int)
#define WS_DRW    (WS_SMP + Bn)            // 64 (int)

// ---------------- threefry2x32 (Random123 / JAX schedule) ----------------
__device__ __forceinline__ void tf2x32(uint32_t k0, uint32_t k1,
                                       uint32_t x0, uint32_t x1,
                                       uint32_t& o0, uint32_t& o1) {
  uint32_t ks2 = k0 ^ k1 ^ 0x1BD11BDAu;
  x0 += k0; x1 += k1;
#define TFR(r) { x0 += x1; x1 = (x1 << r) | (x1 >> (32 - r)); x1 ^= x0; }
  TFR(13) TFR(15) TFR(26) TFR(6)  x0 += k1;  x1 += ks2 + 1u;
  TFR(17) TFR(29) TFR(16) TFR(24) x0 += ks2; x1 += k0 + 2u;
  TFR(13) TFR(15) TFR(26) TFR(6)  x0 += k0;  x1 += k1 + 3u;
  TFR(17) TFR(29) TFR(16) TFR(24) x0 += k1;  x1 += ks2 + 4u;
  TFR(13) TFR(15) TFR(26) TFR(6)  x0 += ks2; x1 += k0 + 5u;
#undef TFR
  o0 = x0; o1 = x1;
}

// random_bits(key, 32, (total,))[i]
__device__ __forceinline__ uint32_t jax_bits32(uint32_t k0, uint32_t k1,
                                               uint32_t i, uint32_t total) {
#if JAX_PARTITIONABLE
  uint32_t o0, o1; tf2x32(k0, k1, 0u, i, o0, o1); return o0 ^ o1;
#else
  uint32_t half = total >> 1;
  uint32_t o0, o1;
  if (i < half) { tf2x32(k0, k1, i, i + half, o0, o1); return o0; }
  tf2x32(k0, k1, i - half, i, o0, o1); return o1;
#endif
}

// split(key, num)[idx]
__device__ __forceinline__ void jax_splitkey(uint32_t k0, uint32_t k1,
                                             uint32_t idx, uint32_t num,
                                             uint32_t& s0, uint32_t& s1) {
#if JAX_PARTITIONABLE
  tf2x32(k0, k1, 0u, idx, s0, s1);
#else
  // original: counts = iota(2*num); out[j<num]=o0(tf(j, j+num)); out[j>=num]=o1(tf(j-num, j))
  uint32_t j0 = 2 * idx, j1 = 2 * idx + 1;
  uint32_t r0, r1;
  if (j0 < num) { tf2x32(k0, k1, j0, j0 + num, r0, r1); s0 = r0; }
  else          { tf2x32(k0, k1, j0 - num, j0, r0, r1); s0 = r1; }
  if (j1 < num) { tf2x32(k0, k1, j1, j1 + num, r0, r1); s1 = r0; }
  else          { tf2x32(k0, k1, j1 - num, j1, r0, r1); s1 = r1; }
#endif
}

__device__ __forceinline__ float bits_to_unit(uint32_t bits) {
  // (bits >> 9 | 0x3F800000) viewed as float, minus 1.0  ->  [0, 1)
  return __uint_as_float((bits >> 9) | 0x3F800000u) - 1.0f;
}

// ---------------- kernels ----------------

__global__ void init_k(float* h0, int* sampled) {
  int i = blockIdx.x * 256 + threadIdx.x;
  if (i < Bn * Hn) h0[i] = 0.0f;
  if (i < Bn) sampled[i] = 0;
}

// G[b,n] = x[b].w_ih[n] + h[b].w_hh[n] + b_ih[n] + b_hh[n]   (n in [0,1536), K=768)
// GHN[b,j] = h[b].w_hh[1024+j] + b_hh[1024+j]                (j in [0,512),  K=512)
// x[b] = emb[sampled[b]].  Tiles: BM=64 (all b), BN=16, BK=32.
__global__ void gru_gemm(const float* __restrict__ emb,
                         const float* __restrict__ w_ih, const float* __restrict__ b_ih,
                         const float* __restrict__ w_hh, const float* __restrict__ b_hh,
                         const float* __restrict__ h_prev, const int* __restrict__ sampled,
                         float* __restrict__ G, float* __restrict__ GHN) {
  const int blk = blockIdx.x;
  const bool isG = blk < 96;
  const int col0 = isG ? blk * 16 : (blk - 96) * 16;
  const int K = isG ? (En + Hn) : Hn;

  __shared__ float As[32][65];
  __shared__ float Bs[32][17];

  const int tid = threadIdx.x;
  const int tx = tid & 15;   // col within tile
  const int tyy = tid >> 4;  // b-group 0..15
  float acc[4] = {0.f, 0.f, 0.f, 0.f};

  const int ab = tid >> 2;            // 0..63 (A row)
  const int ak = (tid & 3) * 8;       // 0,8,16,24
  const int smp = sampled[ab];

  for (int k0 = 0; k0 < K; k0 += 32) {
    // A tile: 64 x 32, thread loads 8 consecutive k
    {
      const int kg = k0 + ak;
      const float* src;
      if (isG) src = (kg < En) ? (emb + (size_t)smp * En + kg)
                               : (h_prev + (size_t)ab * Hn + (kg - En));
      else     src = h_prev + (size_t)ab * Hn + kg;
      float4 v0 = *(const float4*)(src);
      float4 v1 = *(const float4*)(src + 4);
      As[ak + 0][ab] = v0.x; As[ak + 1][ab] = v0.y;
      As[ak + 2][ab] = v0.z; As[ak + 3][ab] = v0.w;
      As[ak + 4][ab] = v1.x; As[ak + 5][ab] = v1.y;
      As[ak + 6][ab] = v1.z; As[ak + 7][ab] = v1.w;
    }
    // B tile: 16 cols x 32 k, threads 0..127 load float4 each
    if (tid < 128) {
      const int c = tid >> 3;            // 0..15
      const int kk = (tid & 7) * 4;      // 0..28
      const int kg = k0 + kk;
      const int col = col0 + c;
      const float* src;
      if (isG) src = (kg < En) ? (w_ih + (size_t)col * En + kg)
                               : (w_hh + (size_t)col * Hn + (kg - En));
      else     src = w_hh + (size_t)(2 * Hn + col) * Hn + kg;
      float4 vv = *(const float4*)src;
      Bs[kk + 0][c] = vv.x; Bs[kk + 1][c] = vv.y;
      Bs[kk + 2][c] = vv.z; Bs[kk + 3][c] = vv.w;
    }
    __syncthreads();
#pragma unroll
    for (int k = 0; k < 32; k++) {
      const float w = Bs[k][tx];
#pragma unroll
      for (int i = 0; i < 4; i++) acc[i] = fmaf(As[k][tyy * 4 + i], w, acc[i]);
    }
    __syncthreads();
  }

  const int col = col0 + tx;
  if (isG) {
    const float bias = b_ih[col] + b_hh[col];
#pragma unroll
    for (int i = 0; i < 4; i++) {
      const int b = tyy * 4 + i;
      G[(size_t)b * (3 * Hn) + col] = acc[i] + bias;
    }
  } else {
    const float bias = b_hh[2 * Hn + col];
#pragma unroll
    for (int i = 0; i < 4; i++) {
      const int b = tyy * 4 + i;
      GHN[(size_t)b * Hn + col] = acc[i] + bias;
    }
  }
}

__global__ void gates_k(const float* __restrict__ G, const float* __restrict__ GHN,
                        const float* __restrict__ h_prev, float* __restrict__ h_new) {
  const int idx = blockIdx.x * 256 + threadIdx.x;  // 0..32767
  const int b = idx >> 9, j = idx & (Hn - 1);
  const float gr = G[(size_t)b * (3 * Hn) + j];
  const float gz = G[(size_t)b * (3 * Hn) + Hn + j];
  const float gn = G[(size_t)b * (3 * Hn) + 2 * Hn + j];
  const float ghn = GHN[(size_t)b * Hn + j];
  const float r = 1.0f / (1.0f + expf(-gr));
  const float z = 1.0f / (1.0f + expf(-gz));
  const float n = tanhf((gn - ghn) + r * ghn);
  const float hp = h_prev[(size_t)b * Hn + j];
  h_new[(size_t)b * Hn + j] = (1.0f - z) * n + z * hp;
}

// logits: C[b,v] = h[b].w_out[v] + b_out[v] -> out_dist[((b*T)+t)*V + v]
// BM=64, BN=64, BK=32; 256 threads; thread = 4x4 micro-tile
__global__ void logits_gemm(const float* __restrict__ h, const float* __restrict__ w_out,
                            const float* __restrict__ b_out, float* __restrict__ out_dist,
                            int t) {
  __shared__ float As[32][68];
  __shared__ float Bs[32][68];
  const int tid = threadIdx.x;
  const int v0 = blockIdx.x * 64;
  const int tx = tid & 15, ty = tid >> 4;
  float acc[4][4] = {};

  const int ab = tid >> 2;        // 0..63
  const int ak = (tid & 3) * 8;   // 0,8,16,24

  for (int k0 = 0; k0 < Hn; k0 += 32) {
    {
      const float* sa = h + (size_t)ab * Hn + k0 + ak;
      float4 a0 = *(const float4*)(sa);
      float4 a1 = *(const float4*)(sa + 4);
      As[ak + 0][ab] = a0.x; As[ak + 1][ab] = a0.y;
      As[ak + 2][ab] = a0.z; As[ak + 3][ab] = a0.w;
      As[ak + 4][ab] = a1.x; As[ak + 5][ab] = a1.y;
      As[ak + 6][ab] = a1.z; As[ak + 7][ab] = a1.w;
      const float* sb = w_out + (size_t)(v0 + ab) * Hn + k0 + ak;
      float4 b0 = *(const float4*)(sb);
      float4 b1 = *(const float4*)(sb + 4);
      Bs[ak + 0][ab] = b0.x; Bs[ak + 1][ab] = b0.y;
      Bs[ak + 2][ab] = b0.z; Bs[ak + 3][ab] = b0.w;
      Bs[ak + 4][ab] = b1.x; Bs[ak + 5][ab] = b1.y;
      Bs[ak + 6][ab] = b1.z; Bs[ak + 7][ab] = b1.w;
    }
    __syncthreads();
#pragma unroll
    for (int k = 0; k < 32; k++) {
      float a[4], bb[4];
#pragma unroll
      for (int i = 0; i < 4; i++) a[i] = As[k][ty * 4 + i];
#pragma unroll
      for (int j = 0; j < 4; j++) bb[j] = Bs[k][tx * 4 + j];
#pragma unroll
      for (int i = 0; i < 4; i++)
#pragma unroll
        for (int j = 0; j < 4; j++) acc[i][j] = fmaf(a[i], bb[j], acc[i][j]);
    }
    __syncthreads();
  }

#pragma unroll
  for (int i = 0; i < 4; i++) {
    const int b = ty * 4 + i;
    const int v = v0 + tx * 4;
    float4 o;
    o.x = acc[i][0] + b_out[v + 0];
    o.y = acc[i][1] + b_out[v + 1];
    o.z = acc[i][2] + b_out[v + 2];
    o.w = acc[i][3] + b_out[v + 3];
    *(float4*)(out_dist + (size_t)(b * Tn + t) * Vn + v) = o;
  }
}

__global__ void rowstat_k(const float* __restrict__ out_dist,
                          float* __restrict__ rowmax, float* __restrict__ rowlse, int t) {
  const int b = blockIdx.x;
  const float* z = out_dist + (size_t)(b * Tn + t) * Vn;
  __shared__ float red[256];
  const int tid = threadIdx.x;
  float m = -INFINITY;
  for (int v = tid; v < Vn; v += 256) m = fmaxf(m, z[v]);
  red[tid] = m; __syncthreads();
  for (int s = 128; s > 0; s >>= 1) {
    if (tid < s) red[tid] = fmaxf(red[tid], red[tid + s]);
    __syncthreads();
  }
  m = red[0]; __syncthreads();
  float s = 0.f;
  for (int v = tid; v < Vn; v += 256) s += expf(z[v] - m);
  red[tid] = s; __syncthreads();
  for (int st = 128; st > 0; st >>= 1) {
    if (tid < st) red[tid] += red[tid + st];
    __syncthreads();
  }
  if (tid == 0) { rowmax[b] = m; rowlse[b] = logf(red[0]); }
}

// Normalize z->dist in place, accumulate probs (mean over b), Gumbel argmax per row.
// grid = 64 rows x 8 chunks of 4000 v
__global__ void sample_k(float* __restrict__ out_dist, float* __restrict__ probs,
                         const float* __restrict__ rowmax, const float* __restrict__ rowlse,
                         float* __restrict__ best_score, float* __restrict__ best_dist,
                         int* __restrict__ best_idx, int* __restrict__ draw, int t) {
  const int b = blockIdx.x >> 3;
  const int ch = blockIdx.x & 7;
  const int tid = threadIdx.x;

  // key chain: root=(0,1) -> key_t -> (k_eps, k_gum)
  uint32_t kt0, kt1, ke0, ke1, kg0, kg1;
  jax_splitkey(0u, 1u, (uint32_t)t, (uint32_t)Tn, kt0, kt1);
  jax_splitkey(kt0, kt1, 0u, 2u, ke0, ke1);
  jax_splitkey(kt0, kt1, 1u, 2u, kg0, kg1);

  // eps draw for row b
  const uint32_t ebits = jax_bits32(ke0, ke1, (uint32_t)b, (uint32_t)Bn);
  const float ue = bits_to_unit(ebits);
  const int dr = (0.1f >= ue) ? 1 : 0;

  const float m = rowmax[b], l = rowlse[b];
  const float LU = -logf((float)Vn);
  float* zrow = out_dist + (size_t)(b * Tn + t) * Vn;

  float bs = -INFINITY; int bi = Vn; float bd = 0.f;
  const int vend = (ch + 1) * (Vn / 8);
  for (int v = ch * (Vn / 8) + tid; v < vend; v += 256) {
    const float zv = zrow[v];
    const float d = (zv - m) - l;
    zrow[v] = d;
    const float p = expf(d);
    atomicAdd(&probs[(size_t)t * Vn + v], p * 0.015625f);
    const uint32_t i = (uint32_t)(b * Vn + v);
    const uint32_t bits = jax_bits32(kg0, kg1, i, (uint32_t)(Bn * Vn));
    const float f = bits_to_unit(bits);
    const float u = fmaxf(1e-9f, f + 1e-9f);
    const float gl = logf(-logf(u));
    const float deps = dr ? LU : d;
    const float sc = deps - gl;
    if (sc > bs) { bs = sc; bi = v; bd = d; }
  }

  __shared__ float ss[256]; __shared__ int si[256]; __shared__ float sd[256];
  ss[tid] = bs; si[tid] = bi; sd[tid] = bd; __syncthreads();
  for (int st = 128; st > 0; st >>= 1) {
    if (tid < st) {
      const float s2 = ss[tid + st]; const int i2 = si[tid + st];
      if (s2 > ss[tid] || (s2 == ss[tid] && i2 < si[tid])) {
        ss[tid] = s2; si[tid] = i2; sd[tid] = sd[tid + st];
      }
    }
    __syncthreads();
  }
  if (tid == 0) {
    const int o = b * 8 + ch;
    best_score[o] = ss[0]; best_idx[o] = si[0]; best_dist[o] = sd[0];
    if (ch == 0) draw[b] = dr;
  }
}

__global__ void finalize_k(const float* __restrict__ best_score,
                           const float* __restrict__ best_dist,
                           const int* __restrict__ best_idx,
                           const int* __restrict__ draw,
                           int* __restrict__ sampled, float* __restrict__ out, int t) {
  const int b = threadIdx.x;  // 64 threads
  float bs = -INFINITY; int bi = 0; float bd = 0.f;
  for (int c = 0; c < 8; c++) {
    const float s = best_score[b * 8 + c];
    const int i = best_idx[b * 8 + c];
    if (s > bs || (s == bs && i < bi)) { bs = s; bi = i; bd = best_dist[b * 8 + c]; }
  }
  sampled[b] = bi;
  out[OUT_SAMP + b * Tn + t] = (float)bi;
  out[OUT_LOGP + b * Tn + t] = bd;
  const float onp = fminf(fmaxf(expf(bd), 1e-8f), 1.0f);
  const float LU = -logf((float)Vn);
  const float deps = draw[b] ? LU : bd;
  const float offp = fminf(fmaxf(expf(deps), 1e-8f), 1.0f);
  out[OUT_CORR + b * Tn + t] = onp / offp;
}

// ---------------- host ----------------
extern "C" void kernel_launch(void* const* d_in, const int* in_sizes, int n_in,
                              void* d_out, int out_size, void* d_ws, size_t ws_size,
                              hipStream_t stream) {
  const float* emb   = (const float*)d_in[0];
  const float* w_ih  = (const float*)d_in[1];
  const float* b_ih  = (const float*)d_in[2];
  const float* w_hh  = (const float*)d_in[3];
  const float* b_hh  = (const float*)d_in[4];
  const float* w_out = (const float*)d_in[5];
  const float* b_out = (const float*)d_in[6];
  float* out = (float*)d_out;
  float* ws  = (float*)d_ws;

  float* h_buf[2] = { ws + WS_H0, ws + WS_H1 };
  float* G    = ws + WS_G;
  float* GHN  = ws + WS_GHN;
  float* rmax = ws + WS_RMAX;
  float* rlse = ws + WS_RLSE;
  float* bsc  = ws + WS_BSC;
  float* bdi  = ws + WS_BDI;
  int*   bix  = (int*)(ws + WS_BIX);
  int*   smp  = (int*)(ws + WS_SMP);
  int*   drw  = (int*)(ws + WS_DRW);

  // probs region must start at zero (out is poisoned before every call)
  hipMemsetAsync(out + OUT_PROB, 0, (size_t)Tn * Vn * sizeof(float), stream);
  init_k<<<(Bn * Hn + 255) / 256, 256, 0, stream>>>(h_buf[0], smp);

  for (int t = 0; t < Tn; t++) {
    float* hp = h_buf[t & 1];
    float* hn = h_buf[(t + 1) & 1];
    gru_gemm<<<128, 256, 0, stream>>>(emb, w_ih, b_ih, w_hh, b_hh, hp, smp, G, GHN);
    gates_k<<<(Bn * Hn) / 256, 256, 0, stream>>>(G, GHN, hp, hn);
    logits_gemm<<<Vn / 64, 256, 0, stream>>>(hn, w_out, b_out, out + OUT_DIST, t);
    rowstat_k<<<Bn, 256, 0, stream>>>(out + OUT_DIST, rmax, rlse, t);
    sample_k<<<Bn * 8, 256, 0, stream>>>(out + OUT_DIST, out + OUT_PROB, rmax, rlse,
                                         bsc, bdi, bix, drw, t);
    finalize_k<<<1, 64, 0, stream>>>(bsc, bdi, bix, drw, smp, out, t);
  }
}